// Round 1
// baseline (372.258 us; speedup 1.0000x reference)
//
#include <hip/hip_runtime.h>
#include <math.h>

#define BATCH 4
#define SEQ 4096
#define DM 1024
#define NS 256
#define MROWS (BATCH*SEQ)   // 16384

#define NCHUNK 64
#define CLEN (SEQ/NCHUNK)   // 64; lam^CLEN computed by 6 squarings below

// C[m,n] = sum_k A[m,k] * Bm[n,k]   (+ optional Dvec[n]*U[m,n] epilogue)
// A: [M,K] row-major, Bm: [N,K] row-major, C: [M,N] row-major.
// Tile 64x64, BK=16, 256 threads, 4x4 acc per thread.
template<bool FUSE_DU>
__global__ __launch_bounds__(256)
void gemm_abt(const float* __restrict__ A, const float* __restrict__ Bm,
              float* __restrict__ C, int M, int N, int K,
              const float* __restrict__ Dvec, const float* __restrict__ U)
{
    // +4 pad keeps 16B alignment for float4 LDS reads and breaks pow2 strides
    __shared__ float As[16][68];
    __shared__ float Bs[16][68];

    const int tid = threadIdx.x;
    const int tx = tid & 15;   // n micro-index
    const int ty = tid >> 4;   // m micro-index
    const int m0 = blockIdx.x * 64;
    const int n0 = blockIdx.y * 64;

    float acc[4][4] = {};

    for (int k0 = 0; k0 < K; k0 += 16) {
        #pragma unroll
        for (int i = 0; i < 4; ++i) {
            int r = ty + 16*i;
            As[tx][r] = A[(size_t)(m0 + r)*K + k0 + tx];
            Bs[tx][r] = Bm[(size_t)(n0 + r)*K + k0 + tx];
        }
        __syncthreads();
        #pragma unroll
        for (int kk = 0; kk < 16; ++kk) {
            const float4 av = *(const float4*)&As[kk][ty*4];
            const float4 bv = *(const float4*)&Bs[kk][tx*4];
            const float a[4] = {av.x, av.y, av.z, av.w};
            const float b[4] = {bv.x, bv.y, bv.z, bv.w};
            #pragma unroll
            for (int i = 0; i < 4; ++i)
                #pragma unroll
                for (int j = 0; j < 4; ++j)
                    acc[i][j] = fmaf(a[i], b[j], acc[i][j]);
        }
        __syncthreads();
    }

    #pragma unroll
    for (int i = 0; i < 4; ++i) {
        const size_t m = (size_t)(m0 + ty*4 + i);
        float4 v = make_float4(acc[i][0], acc[i][1], acc[i][2], acc[i][3]);
        if (FUSE_DU) {
            const float4 dv = *(const float4*)&Dvec[n0 + tx*4];
            const float4 uv = *(const float4*)&U[m*N + n0 + tx*4];
            v.x = fmaf(dv.x, uv.x, v.x);
            v.y = fmaf(dv.y, uv.y, v.y);
            v.z = fmaf(dv.z, uv.z, v.z);
            v.w = fmaf(dv.w, uv.w, v.w);
        }
        *(float4*)&C[m*N + n0 + tx*4] = v;
    }
}

__device__ __forceinline__ float sigmoidf_dev(float x) {
    return 1.0f / (1.0f + expf(-x));
}

// Phase 1: local scan with h0=0, in-place on Bu -> hs_local. Writes chunk-final h.
// grid: (NCHUNK, BATCH), block 256 (thread = state index n).
__global__ __launch_bounds__(256)
void scan_local(float* __restrict__ hs, const float* __restrict__ log_lambda,
                float* __restrict__ chunk_final)
{
    const int n = threadIdx.x;
    const int c = blockIdx.x;
    const int b = blockIdx.y;
    const float lam = sigmoidf_dev(log_lambda[n]);
    const size_t base = ((size_t)b*SEQ + (size_t)c*CLEN)*NS + n;
    float h = 0.0f;
    for (int t = 0; t < CLEN; ++t) {
        h = fmaf(lam, h, hs[base + (size_t)t*NS]);
        hs[base + (size_t)t*NS] = h;
    }
    chunk_final[((size_t)b*NCHUNK + c)*NS + n] = h;
}

// Phase 2+3: each (b,c) workgroup builds its exclusive carry from the
// chunk-local finals (carry = lam^CLEN*carry + final[j], j<c) and applies
// hs_global[t] = hs_local[t] + lam^(t+1)*carry.
__global__ __launch_bounds__(256)
void scan_fixup(float* __restrict__ hs, const float* __restrict__ log_lambda,
                const float* __restrict__ chunk_final)
{
    const int n = threadIdx.x;
    const int c = blockIdx.x;
    const int b = blockIdx.y;
    if (c == 0) return;
    const float lam = sigmoidf_dev(log_lambda[n]);
    float lamL = lam;                       // lam^64 via 6 squarings (CLEN==64)
    #pragma unroll
    for (int i = 0; i < 6; ++i) lamL *= lamL;

    float carry = 0.0f;
    for (int j = 0; j < c; ++j)
        carry = fmaf(lamL, carry, chunk_final[((size_t)b*NCHUNK + j)*NS + n]);

    float p = lam;
    const size_t base = ((size_t)b*SEQ + (size_t)c*CLEN)*NS + n;
    for (int t = 0; t < CLEN; ++t) {
        hs[base + (size_t)t*NS] = fmaf(p, carry, hs[base + (size_t)t*NS]);
        p *= lam;
    }
}

extern "C" void kernel_launch(void* const* d_in, const int* in_sizes, int n_in,
                              void* d_out, int out_size, void* d_ws, size_t ws_size,
                              hipStream_t stream) {
    const float* u          = (const float*)d_in[0];  // [4,4096,1024]
    const float* log_lambda = (const float*)d_in[1];  // [256]
    const float* B_w        = (const float*)d_in[2];  // [256,1024]
    const float* C_w        = (const float*)d_in[3];  // [1024,256]
    const float* Dv         = (const float*)d_in[4];  // [1024]
    float* y  = (float*)d_out;                        // [4,4096,1024]

    float* Bu          = (float*)d_ws;                       // 16 MB: [16384,256]
    float* chunk_final = Bu + (size_t)MROWS*NS;              // 256 KB: [4,64,256]

    dim3 blk(256);

    // 1) Bu = u . B_w^T   (M=16384, N=256, K=1024)
    gemm_abt<false><<<dim3(MROWS/64, NS/64), blk, 0, stream>>>(
        u, B_w, Bu, MROWS, NS, DM, nullptr, nullptr);

    // 2) chunked scan over seq, in-place
    scan_local<<<dim3(NCHUNK, BATCH), blk, 0, stream>>>(Bu, log_lambda, chunk_final);
    scan_fixup<<<dim3(NCHUNK, BATCH), blk, 0, stream>>>(Bu, log_lambda, chunk_final);

    // 3) y = hs . C_w^T + D*u   (M=16384, N=1024, K=256)
    gemm_abt<true><<<dim3(MROWS/64, DM/64), blk, 0, stream>>>(
        Bu, C_w, y, MROWS, DM, NS, Dv, u);
}

// Round 2
// 245.040 us; speedup vs baseline: 1.5192x; 1.5192x over previous
//
#include <hip/hip_runtime.h>
#include <math.h>

typedef unsigned short ushort_t;
typedef __bf16 v8bf __attribute__((ext_vector_type(8)));
typedef float f32x4 __attribute__((ext_vector_type(4)));

#define BATCH 4
#define SEQ 4096
#define DM 1024
#define NS 256
#define MROWS (BATCH*SEQ)   // 16384

#define NCH 256
#define CL (SEQ/NCH)        // 16

#define BM 128
#define BN 128
#define BK 32

typedef __attribute__((address_space(1))) void as1_void;
typedef __attribute__((address_space(3))) void as3_void;

__device__ __forceinline__ void gl_lds16(const void* g, void* l) {
    // 16B global -> LDS direct (gfx950). LDS dest must be uniform-base + lane*16.
    __builtin_amdgcn_global_load_lds((as1_void*)g, (as3_void*)l, 16, 0, 0);
}

__device__ __forceinline__ ushort_t f2bf(float f) {
    unsigned u = __builtin_bit_cast(unsigned, f);
    u += 0x7fff + ((u >> 16) & 1);          // RNE
    return (ushort_t)(u >> 16);
}

// ---------------------------------------------------------------------------
// bf16 MFMA GEMM, C[m,n] = sum_k A[m,k]*B[n,k]  (both operands K-contiguous)
// 128x128 tile, BK=32, 256 threads (4 waves, 2x2 of 64x64), fp32 output.
// Optional epilogue: C += Dvec[n]*U[m,n].
// ---------------------------------------------------------------------------
template<bool FUSE_DU>
__global__ __launch_bounds__(256)
void gemm_bt_mfma(const ushort_t* __restrict__ A,  // [M,K] bf16
                  const ushort_t* __restrict__ B,  // [N,K] bf16
                  float* __restrict__ C,           // [M,N] fp32
                  int M, int N, int K,
                  const float* __restrict__ Dvec, const float* __restrict__ U)
{
    __shared__ __align__(16) ushort_t As[BM*BK];   // 8 KB, [128][32]
    __shared__ __align__(16) ushort_t Bs[BN*BK];   // 8 KB

    const int tid  = threadIdx.x;
    const int lane = tid & 63;
    const int wave = tid >> 6;      // 0..3
    const int wrow = wave >> 1;     // 0..1 -> m offset 64*wrow
    const int wcol = wave & 1;      // 0..1 -> n offset 64*wcol
    const int m0 = blockIdx.x * BM;
    const int n0 = blockIdx.y * BN;

    const int fr = lane & 15;       // fragment row (m or n within 16)
    const int fq = lane >> 4;       // quad -> k offset fq*8

    f32x4 acc[4][4] = {};

    // staging chunk ids: 512 chunks of 16B per tile; 2 per thread
    const int ch0 = wave*128 + lane;        // j=0
    const int ch1 = ch0 + 64;               // j=1

    for (int k0 = 0; k0 < K; k0 += BK) {
        __syncthreads();   // previous iteration's LDS reads complete
        {
            int r0 = ch0 >> 2, c0 = (ch0 & 3) * 8;
            int r1 = ch1 >> 2, c1 = (ch1 & 3) * 8;
            gl_lds16(&A[(size_t)(m0 + r0)*K + k0 + c0], &As[ch0*8]);
            gl_lds16(&B[(size_t)(n0 + r0)*K + k0 + c0], &Bs[ch0*8]);
            gl_lds16(&A[(size_t)(m0 + r1)*K + k0 + c1], &As[ch1*8]);
            gl_lds16(&B[(size_t)(n0 + r1)*K + k0 + c1], &Bs[ch1*8]);
        }
        __syncthreads();   // staging visible to all waves

        v8bf af[4], bf[4];
        #pragma unroll
        for (int mi = 0; mi < 4; ++mi)
            af[mi] = *reinterpret_cast<const v8bf*>(&As[(wrow*64 + mi*16 + fr)*BK + fq*8]);
        #pragma unroll
        for (int ni = 0; ni < 4; ++ni)
            bf[ni] = *reinterpret_cast<const v8bf*>(&Bs[(wcol*64 + ni*16 + fr)*BK + fq*8]);

        #pragma unroll
        for (int mi = 0; mi < 4; ++mi)
            #pragma unroll
            for (int ni = 0; ni < 4; ++ni)
                acc[mi][ni] = __builtin_amdgcn_mfma_f32_16x16x32_bf16(
                                  af[mi], bf[ni], acc[mi][ni], 0, 0, 0);
    }

    // Epilogue. C/D layout: col = lane&15, row = (lane>>4)*4 + reg
    const int orow = m0 + wrow*64 + (lane >> 4)*4;
    const int ocol = n0 + wcol*64 + (lane & 15);
    #pragma unroll
    for (int mi = 0; mi < 4; ++mi) {
        #pragma unroll
        for (int ni = 0; ni < 4; ++ni) {
            const int col = ocol + ni*16;
            #pragma unroll
            for (int r = 0; r < 4; ++r) {
                const size_t idx = (size_t)(orow + mi*16 + r) * N + col;
                float v = acc[mi][ni][r];
                if (FUSE_DU) v = fmaf(Dvec[col], U[idx], v);
                C[idx] = v;
            }
        }
    }
}

// ---------------------------------------------------------------------------
// fp32 -> bf16 conversion, 4 elems/thread
// ---------------------------------------------------------------------------
__global__ __launch_bounds__(256)
void cvt4(const float4* __restrict__ in, ushort_t* __restrict__ out, int n4)
{
    int i = blockIdx.x * 256 + threadIdx.x;
    if (i >= n4) return;
    float4 v = in[i];
    ushort4 o;
    o.x = f2bf(v.x); o.y = f2bf(v.y); o.z = f2bf(v.z); o.w = f2bf(v.w);
    *(ushort4*)&out[4*(size_t)i] = o;
}

// ---------------------------------------------------------------------------
// Scan phase 1: local scan (h0=0) in place over Bu, CL=16 steps.
// grid (NCH, BATCH), block 256 (thread = state).
// ---------------------------------------------------------------------------
__global__ __launch_bounds__(256)
void scan_local(float* __restrict__ hs, const float* __restrict__ ll,
                float* __restrict__ cf)
{
    const int n = threadIdx.x, c = blockIdx.x, b = blockIdx.y;
    const float lam = 1.0f / (1.0f + expf(-ll[n]));
    const size_t base = ((size_t)b*SEQ + (size_t)c*CL)*NS + n;

    float v[CL];
    #pragma unroll
    for (int t = 0; t < CL; ++t) v[t] = hs[base + (size_t)t*NS];
    float h = 0.0f;
    #pragma unroll
    for (int t = 0; t < CL; ++t) { h = fmaf(lam, h, v[t]); v[t] = h; }
    #pragma unroll
    for (int t = 0; t < CL; ++t) hs[base + (size_t)t*NS] = v[t];
    cf[((size_t)b*NCH + c)*NS + n] = h;
}

// ---------------------------------------------------------------------------
// Scan phase 2: build exclusive carry from chunk finals, apply, emit bf16 hs.
// ---------------------------------------------------------------------------
__global__ __launch_bounds__(256)
void scan_fixup(const float* __restrict__ hs, const float* __restrict__ ll,
                const float* __restrict__ cf, ushort_t* __restrict__ hs16)
{
    const int n = threadIdx.x, c = blockIdx.x, b = blockIdx.y;
    const float lam = 1.0f / (1.0f + expf(-ll[n]));
    float lamL = lam;                      // lam^16 via 4 squarings (CL==16)
    #pragma unroll
    for (int i = 0; i < 4; ++i) lamL *= lamL;

    const float* cfb = cf + (size_t)b*NCH*NS + n;
    float carry = 0.0f;
    for (int j = 0; j < c; ++j) carry = fmaf(lamL, carry, cfb[(size_t)j*NS]);

    const size_t base = ((size_t)b*SEQ + (size_t)c*CL)*NS + n;
    float v[CL];
    #pragma unroll
    for (int t = 0; t < CL; ++t) v[t] = hs[base + (size_t)t*NS];
    float p = lam;
    #pragma unroll
    for (int t = 0; t < CL; ++t) { v[t] = fmaf(p, carry, v[t]); p *= lam; }
    #pragma unroll
    for (int t = 0; t < CL; ++t) hs16[base + (size_t)t*NS] = f2bf(v[t]);
}

// ---------------------------------------------------------------------------
extern "C" void kernel_launch(void* const* d_in, const int* in_sizes, int n_in,
                              void* d_out, int out_size, void* d_ws, size_t ws_size,
                              hipStream_t stream) {
    const float* u          = (const float*)d_in[0];  // [4,4096,1024]
    const float* log_lambda = (const float*)d_in[1];  // [256]
    const float* B_w        = (const float*)d_in[2];  // [256,1024]
    const float* C_w        = (const float*)d_in[3];  // [1024,256]
    const float* Dv         = (const float*)d_in[4];  // [1024]
    float* y  = (float*)d_out;                        // [4,4096,1024]

    // ws layout (hs16 aliases u16: u16 is dead after GEMM1)
    char* w = (char*)d_ws;
    ushort_t* u16  = (ushort_t*)w;                          // 33.55 MB
    ushort_t* hs16 = (ushort_t*)w;                          // 8.39 MB (alias)
    float*    Bu   = (float*)(w + 33554432);                // 16.78 MB
    ushort_t* Bw16 = (ushort_t*)(w + 33554432 + 16777216);  // 512 KB
    ushort_t* Cw16 = (ushort_t*)(w + 33554432 + 16777216 + 524288);
    float*    cf   = (float*)(w + 33554432 + 16777216 + 1048576); // 1 MB

    dim3 blk(256);

    // 0) conversions to bf16
    cvt4<<<dim3(MROWS*DM/4/256), blk, 0, stream>>>((const float4*)u,   u16,  MROWS*DM/4);
    cvt4<<<dim3(NS*DM/4/256),    blk, 0, stream>>>((const float4*)B_w, Bw16, NS*DM/4);
    cvt4<<<dim3(DM*NS/4/256),    blk, 0, stream>>>((const float4*)C_w, Cw16, DM*NS/4);

    // 1) Bu = u . B_w^T   (M=16384, N=256, K=1024)
    gemm_bt_mfma<false><<<dim3(MROWS/BM, NS/BN), blk, 0, stream>>>(
        u16, Bw16, Bu, MROWS, NS, DM, nullptr, nullptr);

    // 2) chunked scan over seq (fp32), emit bf16 hs
    scan_local<<<dim3(NCH, BATCH), blk, 0, stream>>>(Bu, log_lambda, cf);
    scan_fixup<<<dim3(NCH, BATCH), blk, 0, stream>>>(Bu, log_lambda, cf, hs16);

    // 3) y = hs . C_w^T + D*u   (M=16384, N=1024, K=256)
    gemm_bt_mfma<true><<<dim3(MROWS/BM, DM/BN), blk, 0, stream>>>(
        hs16, Cw16, y, MROWS, DM, NS, Dv, u);
}

// Round 3
// 187.272 us; speedup vs baseline: 1.9878x; 1.3085x over previous
//
#include <hip/hip_runtime.h>
#include <math.h>

typedef unsigned short ushort_t;
typedef __bf16 v8bf __attribute__((ext_vector_type(8)));
typedef float f32x4 __attribute__((ext_vector_type(4)));

#define BATCH 4
#define SEQ 4096
#define DM 1024
#define NS 256
#define MROWS (BATCH*SEQ)   // 16384

#define NCH 128
#define CL (SEQ/NCH)        // 32; lam^CL via 5 squarings

#define BM 128
#define BN 128
#define BK 32

typedef __attribute__((address_space(1))) void as1_void;
typedef __attribute__((address_space(3))) void as3_void;

__device__ __forceinline__ void gl_lds16(const void* g, void* l) {
    __builtin_amdgcn_global_load_lds((as1_void*)g, (as3_void*)l, 16, 0, 0);
}

__device__ __forceinline__ ushort_t f2bf(float f) {
    unsigned u = __builtin_bit_cast(unsigned, f);
    u += 0x7fff + ((u >> 16) & 1);          // RNE
    return (ushort_t)(u >> 16);
}

__device__ __forceinline__ float sigm(float x) { return 1.0f / (1.0f + expf(-x)); }

// ---------------------------------------------------------------------------
// bf16 MFMA GEMM, C[m,n] = sum_k A[m,k]*B[n,k]; 128x128 tile, BK=32,
// 256 threads (2x2 waves of 64x64). Optional epilogue C += Dvec[n]*U[m,n].
// ---------------------------------------------------------------------------
template<bool FUSE_DU>
__global__ __launch_bounds__(256)
void gemm_bt_mfma(const ushort_t* __restrict__ A,  // [M,K] bf16
                  const ushort_t* __restrict__ B,  // [N,K] bf16
                  float* __restrict__ C,           // [M,N] fp32
                  int M, int N, int K,
                  const float* __restrict__ Dvec, const float* __restrict__ U)
{
    __shared__ __align__(16) ushort_t As[BM*BK];   // 8 KB
    __shared__ __align__(16) ushort_t Bs[BN*BK];   // 8 KB

    const int tid  = threadIdx.x;
    const int lane = tid & 63;
    const int wave = tid >> 6;
    const int wrow = wave >> 1;
    const int wcol = wave & 1;
    const int m0 = blockIdx.x * BM;
    const int n0 = blockIdx.y * BN;

    const int fr = lane & 15;
    const int fq = lane >> 4;

    f32x4 acc[4][4] = {};

    const int ch0 = wave*128 + lane;
    const int ch1 = ch0 + 64;

    for (int k0 = 0; k0 < K; k0 += BK) {
        __syncthreads();
        {
            int r0 = ch0 >> 2, c0 = (ch0 & 3) * 8;
            int r1 = ch1 >> 2, c1 = (ch1 & 3) * 8;
            gl_lds16(&A[(size_t)(m0 + r0)*K + k0 + c0], &As[ch0*8]);
            gl_lds16(&B[(size_t)(n0 + r0)*K + k0 + c0], &Bs[ch0*8]);
            gl_lds16(&A[(size_t)(m0 + r1)*K + k0 + c1], &As[ch1*8]);
            gl_lds16(&B[(size_t)(n0 + r1)*K + k0 + c1], &Bs[ch1*8]);
        }
        __syncthreads();

        v8bf af[4], bf[4];
        #pragma unroll
        for (int mi = 0; mi < 4; ++mi)
            af[mi] = *reinterpret_cast<const v8bf*>(&As[(wrow*64 + mi*16 + fr)*BK + fq*8]);
        #pragma unroll
        for (int ni = 0; ni < 4; ++ni)
            bf[ni] = *reinterpret_cast<const v8bf*>(&Bs[(wcol*64 + ni*16 + fr)*BK + fq*8]);

        #pragma unroll
        for (int mi = 0; mi < 4; ++mi)
            #pragma unroll
            for (int ni = 0; ni < 4; ++ni)
                acc[mi][ni] = __builtin_amdgcn_mfma_f32_16x16x32_bf16(
                                  af[mi], bf[ni], acc[mi][ni], 0, 0, 0);
    }

    const int orow = m0 + wrow*64 + (lane >> 4)*4;
    const int ocol = n0 + wcol*64 + (lane & 15);
    #pragma unroll
    for (int mi = 0; mi < 4; ++mi) {
        #pragma unroll
        for (int ni = 0; ni < 4; ++ni) {
            const int col = ocol + ni*16;
            #pragma unroll
            for (int r = 0; r < 4; ++r) {
                const size_t idx = (size_t)(orow + mi*16 + r) * N + col;
                float v = acc[mi][ni][r];
                if (FUSE_DU) v = fmaf(Dvec[col], U[idx], v);
                C[idx] = v;
            }
        }
    }
}

// ---------------------------------------------------------------------------
__global__ __launch_bounds__(256)
void cvt4(const float4* __restrict__ in, ushort_t* __restrict__ out, int n4)
{
    int i = blockIdx.x * 256 + threadIdx.x;
    if (i >= n4) return;
    float4 v = in[i];
    ushort4 o;
    o.x = f2bf(v.x); o.y = f2bf(v.y); o.z = f2bf(v.z); o.w = f2bf(v.w);
    *(ushort4*)&out[4*(size_t)i] = o;
}

// ---------------------------------------------------------------------------
// Scan phase 1: chunk-local final only (h0=0). grid (NCH, BATCH), block=NS.
// ---------------------------------------------------------------------------
__global__ __launch_bounds__(256)
void scan_finals(const float* __restrict__ Bu, const float* __restrict__ ll,
                 float* __restrict__ cf)
{
    const int n = threadIdx.x, c = blockIdx.x, b = blockIdx.y;
    const float lam = sigm(ll[n]);
    const size_t base = ((size_t)b*SEQ + (size_t)c*CL)*NS + n;
    float v[CL];
    #pragma unroll
    for (int t = 0; t < CL; ++t) v[t] = Bu[base + (size_t)t*NS];
    float h = 0.0f;
    #pragma unroll
    for (int t = 0; t < CL; ++t) h = fmaf(lam, h, v[t]);
    cf[((size_t)b*NCH + c)*NS + n] = h;
}

// ---------------------------------------------------------------------------
// Scan phase 2: exclusive carry per chunk. grid (BATCH), block=NS.
// Batched loads (16 ahead) so the serial FMA chain never waits on memory.
// ---------------------------------------------------------------------------
__global__ __launch_bounds__(256)
void carry_scan(const float* __restrict__ ll, const float* __restrict__ cf,
                float* __restrict__ carry)
{
    const int n = threadIdx.x, b = blockIdx.x;
    const float lam = sigm(ll[n]);
    float lamL = lam;                      // lam^32 (CL==32)
    #pragma unroll
    for (int i = 0; i < 5; ++i) lamL *= lamL;

    const float* cfb = cf    + (size_t)b*NCH*NS + n;
    float*       cab = carry + (size_t)b*NCH*NS + n;

    float x = 0.0f;
    for (int c0 = 0; c0 < NCH; c0 += 16) {
        float v[16];
        #pragma unroll
        for (int j = 0; j < 16; ++j) v[j] = cfb[(size_t)(c0 + j)*NS];
        #pragma unroll
        for (int j = 0; j < 16; ++j) {
            cab[(size_t)(c0 + j)*NS] = x;
            x = fmaf(lamL, x, v[j]);
        }
    }
}

// ---------------------------------------------------------------------------
// Scan phase 3: seed with carry, replay recurrence, emit bf16 hs.
// ---------------------------------------------------------------------------
__global__ __launch_bounds__(256)
void scan_apply(const float* __restrict__ Bu, const float* __restrict__ ll,
                const float* __restrict__ carry, ushort_t* __restrict__ hs16)
{
    const int n = threadIdx.x, c = blockIdx.x, b = blockIdx.y;
    const float lam = sigm(ll[n]);
    const size_t base = ((size_t)b*SEQ + (size_t)c*CL)*NS + n;

    float v[CL];
    #pragma unroll
    for (int t = 0; t < CL; ++t) v[t] = Bu[base + (size_t)t*NS];

    float h = carry[((size_t)b*NCH + c)*NS + n];
    #pragma unroll
    for (int t = 0; t < CL; ++t) { h = fmaf(lam, h, v[t]); v[t] = h; }
    #pragma unroll
    for (int t = 0; t < CL; ++t) hs16[base + (size_t)t*NS] = f2bf(v[t]);
}

// ---------------------------------------------------------------------------
extern "C" void kernel_launch(void* const* d_in, const int* in_sizes, int n_in,
                              void* d_out, int out_size, void* d_ws, size_t ws_size,
                              hipStream_t stream) {
    const float* u          = (const float*)d_in[0];
    const float* log_lambda = (const float*)d_in[1];
    const float* B_w        = (const float*)d_in[2];
    const float* C_w        = (const float*)d_in[3];
    const float* Dv         = (const float*)d_in[4];
    float* y  = (float*)d_out;

    // ws layout (hs16 aliases u16: u16 is dead after GEMM1)
    char* w = (char*)d_ws;
    ushort_t* u16  = (ushort_t*)w;                             // 33.55 MB
    ushort_t* hs16 = (ushort_t*)w;                             // 8.39 MB (alias)
    float*    Bu   = (float*)(w + 33554432);                   // 16.78 MB
    ushort_t* Bw16 = (ushort_t*)(w + 33554432 + 16777216);     // 512 KB
    ushort_t* Cw16 = (ushort_t*)(w + 33554432 + 16777216 + 524288);
    float*    cf   = (float*)(w + 33554432 + 16777216 + 1048576);   // 512 KB
    float*    carry= (float*)(w + 33554432 + 16777216 + 1572864);   // 512 KB

    dim3 blk(256);

    // 0) conversions to bf16
    cvt4<<<dim3(MROWS*DM/4/256), blk, 0, stream>>>((const float4*)u,   u16,  MROWS*DM/4);
    cvt4<<<dim3(NS*DM/4/256),    blk, 0, stream>>>((const float4*)B_w, Bw16, NS*DM/4);
    cvt4<<<dim3(DM*NS/4/256),    blk, 0, stream>>>((const float4*)C_w, Cw16, DM*NS/4);

    // 1) Bu = u . B_w^T   (M=16384, N=256, K=1024)
    gemm_bt_mfma<false><<<dim3(MROWS/BM, NS/BN), blk, 0, stream>>>(
        u16, Bw16, Bu, MROWS, NS, DM, nullptr, nullptr);

    // 2) scan: finals -> carries -> apply (emit bf16 hs)
    scan_finals<<<dim3(NCH, BATCH), blk, 0, stream>>>(Bu, log_lambda, cf);
    carry_scan <<<dim3(BATCH),      blk, 0, stream>>>(log_lambda, cf, carry);
    scan_apply <<<dim3(NCH, BATCH), blk, 0, stream>>>(Bu, log_lambda, carry, hs16);

    // 3) y = hs . C_w^T + D*u   (M=16384, N=1024, K=256)
    gemm_bt_mfma<true><<<dim3(MROWS/BM, DM/BN), blk, 0, stream>>>(
        hs16, Cw16, y, MROWS, DM, NS, Dv, u);
}

// Round 4
// 185.141 us; speedup vs baseline: 2.0107x; 1.0115x over previous
//
#include <hip/hip_runtime.h>
#include <math.h>

typedef unsigned short ushort_t;
typedef __bf16 v8bf __attribute__((ext_vector_type(8)));
typedef __bf16 v4bf __attribute__((ext_vector_type(4)));
typedef float  v4f  __attribute__((ext_vector_type(4)));
typedef float  f32x4 __attribute__((ext_vector_type(4)));

#define BATCH 4
#define SEQ 4096
#define DM 1024
#define NS 256
#define MROWS (BATCH*SEQ)   // 16384

#define NCH 128
#define CL (SEQ/NCH)        // 32

#define BM 128
#define BN 128
#define BK 32

typedef __attribute__((address_space(1))) void as1_void;
typedef __attribute__((address_space(3))) void as3_void;

__device__ __forceinline__ void gl_lds16(const void* g, void* l) {
    __builtin_amdgcn_global_load_lds((as1_void*)g, (as3_void*)l, 16, 0, 0);
}

__device__ __forceinline__ ushort_t f2bf(float f) {
    unsigned u = __builtin_bit_cast(unsigned, f);
    u += 0x7fff + ((u >> 16) & 1);          // RNE
    return (ushort_t)(u >> 16);
}

__device__ __forceinline__ float sigm(float x) { return 1.0f / (1.0f + expf(-x)); }

// lam^e for e in [0,31] via precomputed squarings
__device__ __forceinline__ float powk(int e, float l1, float l2, float l4,
                                      float l8, float l16) {
    float w = 1.0f;
    if (e & 1)  w *= l1;
    if (e & 2)  w *= l2;
    if (e & 4)  w *= l4;
    if (e & 8)  w *= l8;
    if (e & 16) w *= l16;
    return w;
}

// ---------------------------------------------------------------------------
// GEMM1 fused: Bu = u . B_w^T  (A fp32 -> cvt in staging), plus chunk-final
// scan coefficients cf[b,c,n] = sum_t lam^(CL-1-t) * Bu[b, c*CL+t, n]
// computed straight from the MFMA accumulators in the epilogue.
// M=16384, N=256, K=1024. 128x128 tile, BK=32, 4 waves (2x2 of 64x64).
// ---------------------------------------------------------------------------
__global__ __launch_bounds__(256)
void gemm1_fused(const float* __restrict__ A,      // u [M,K] fp32
                 const ushort_t* __restrict__ B,   // Bw16 [N,K] bf16
                 float* __restrict__ Bu,           // [M,NS] fp32
                 const float* __restrict__ ll,     // [NS]
                 float* __restrict__ cf)           // [BATCH,NCH,NS]
{
    const int K = DM;
    const int N = NS;
    __shared__ __align__(16) ushort_t As[BM*BK];   // 8 KB bf16
    __shared__ __align__(16) ushort_t Bs[BN*BK];   // 8 KB bf16

    const int tid  = threadIdx.x;
    const int lane = tid & 63;
    const int wave = tid >> 6;
    const int wrow = wave >> 1;
    const int wcol = wave & 1;
    const int m0 = blockIdx.x * BM;
    const int n0 = blockIdx.y * BN;

    const int fr = lane & 15;
    const int fq = lane >> 4;

    f32x4 acc[4][4] = {};

    const int bch0 = wave*128 + lane;   // B staging chunk ids (16B each)
    const int bch1 = bch0 + 64;

    for (int k0 = 0; k0 < K; k0 += BK) {
        __syncthreads();
        // B tile: global_load_lds direct, 512 x 16B chunks, 2/thread
        {
            int r0 = bch0 >> 2, c0 = (bch0 & 3) * 8;
            int r1 = bch1 >> 2, c1 = (bch1 & 3) * 8;
            gl_lds16(&B[(size_t)(n0 + r0)*K + k0 + c0], &Bs[bch0*8]);
            gl_lds16(&B[(size_t)(n0 + r1)*K + k0 + c1], &Bs[bch1*8]);
        }
        // A tile: fp32 global -> cvt -> bf16 LDS. 1024 float4 chunks, 4/thread.
        {
            v4f va[4];
            #pragma unroll
            for (int j = 0; j < 4; ++j) {
                int cid = j*256 + tid;
                int row = cid >> 3;
                int c4  = (cid & 7) * 4;
                va[j] = *(const v4f*)&A[(size_t)(m0 + row)*K + k0 + c4];
            }
            #pragma unroll
            for (int j = 0; j < 4; ++j) {
                int cid = j*256 + tid;
                int row = cid >> 3;
                int c4  = (cid & 7) * 4;
                v4bf o = __builtin_convertvector(va[j], v4bf);
                *(v4bf*)&As[row*BK + c4] = o;
            }
        }
        __syncthreads();

        v8bf af[4], bf[4];
        #pragma unroll
        for (int mi = 0; mi < 4; ++mi)
            af[mi] = *reinterpret_cast<const v8bf*>(&As[(wrow*64 + mi*16 + fr)*BK + fq*8]);
        #pragma unroll
        for (int ni = 0; ni < 4; ++ni)
            bf[ni] = *reinterpret_cast<const v8bf*>(&Bs[(wcol*64 + ni*16 + fr)*BK + fq*8]);

        #pragma unroll
        for (int mi = 0; mi < 4; ++mi)
            #pragma unroll
            for (int ni = 0; ni < 4; ++ni)
                acc[mi][ni] = __builtin_amdgcn_mfma_f32_16x16x32_bf16(
                                  af[mi], bf[ni], acc[mi][ni], 0, 0, 0);
    }

    // ---- write Bu. C/D layout: col = lane&15, row = (lane>>4)*4 + reg ----
    const int orow = m0 + wrow*64 + (lane >> 4)*4;
    const int ocol = n0 + wcol*64 + (lane & 15);
    #pragma unroll
    for (int mi = 0; mi < 4; ++mi)
        #pragma unroll
        for (int ni = 0; ni < 4; ++ni)
            #pragma unroll
            for (int r = 0; r < 4; ++r)
                Bu[(size_t)(orow + mi*16 + r) * N + (ocol + ni*16)] = acc[mi][ni][r];

    // ---- fused chunk finals ----
    // rows of this block = 4 chunks of CL=32; wave (wrow) owns 2 of them.
    // rowin = (mi&1)*16 + (lane>>4)*4 + r ; weight = lam^(31 - rowin)
    const int b_idx  = m0 >> 12;            // m0 / 4096
    const int c_base = (m0 & 4095) >> 5;    // first chunk of this block
    const int base   = (lane >> 4) * 4;

    #pragma unroll
    for (int ni = 0; ni < 4; ++ni) {
        const int col = ocol + ni*16;       // global n in [0,256)
        const float l1  = sigm(ll[col]);
        const float l2  = l1*l1;
        const float l4  = l2*l2;
        const float l8  = l4*l4;
        const float l16 = l8*l8;
        #pragma unroll
        for (int half = 0; half < 2; ++half) {     // chunk within wave's 64 rows
            float f = 0.0f;
            #pragma unroll
            for (int mi2 = 0; mi2 < 2; ++mi2) {
                const int mi = half*2 + mi2;
                // r=3 exponent: 31 - (mi2*16 + base + 3)
                float w = powk(28 - mi2*16 - base, l1, l2, l4, l8, l16);
                f = fmaf(w, acc[mi][ni][3], f);
                w *= l1; f = fmaf(w, acc[mi][ni][2], f);
                w *= l1; f = fmaf(w, acc[mi][ni][1], f);
                w *= l1; f = fmaf(w, acc[mi][ni][0], f);
            }
            // reduce over the 4 lanes sharing this column (lane ^16, ^32)
            f += __shfl_xor(f, 16, 64);
            f += __shfl_xor(f, 32, 64);
            if ((lane >> 4) == 0) {
                const int chunk = c_base + wrow*2 + half;
                cf[((size_t)b_idx*NCH + chunk)*NS + col] = f;
            }
        }
    }
}

// ---------------------------------------------------------------------------
// bf16 MFMA GEMM for y = hs . C_w^T (+ D*u, skipped per-element when D==0)
// ---------------------------------------------------------------------------
__global__ __launch_bounds__(256)
void gemm2_mfma(const ushort_t* __restrict__ A,  // hs16 [M,K] bf16, K=256
                const ushort_t* __restrict__ B,  // Cw16 [N,K] bf16, N=1024
                float* __restrict__ C,           // y [M,N] fp32
                int M, int N, int K,
                const float* __restrict__ Dvec, const float* __restrict__ U)
{
    __shared__ __align__(16) ushort_t As[BM*BK];
    __shared__ __align__(16) ushort_t Bs[BN*BK];

    const int tid  = threadIdx.x;
    const int lane = tid & 63;
    const int wave = tid >> 6;
    const int wrow = wave >> 1;
    const int wcol = wave & 1;
    const int m0 = blockIdx.x * BM;
    const int n0 = blockIdx.y * BN;

    const int fr = lane & 15;
    const int fq = lane >> 4;

    f32x4 acc[4][4] = {};

    const int ch0 = wave*128 + lane;
    const int ch1 = ch0 + 64;

    for (int k0 = 0; k0 < K; k0 += BK) {
        __syncthreads();
        {
            int r0 = ch0 >> 2, c0 = (ch0 & 3) * 8;
            int r1 = ch1 >> 2, c1 = (ch1 & 3) * 8;
            gl_lds16(&A[(size_t)(m0 + r0)*K + k0 + c0], &As[ch0*8]);
            gl_lds16(&B[(size_t)(n0 + r0)*K + k0 + c0], &Bs[ch0*8]);
            gl_lds16(&A[(size_t)(m0 + r1)*K + k0 + c1], &As[ch1*8]);
            gl_lds16(&B[(size_t)(n0 + r1)*K + k0 + c1], &Bs[ch1*8]);
        }
        __syncthreads();

        v8bf af[4], bf[4];
        #pragma unroll
        for (int mi = 0; mi < 4; ++mi)
            af[mi] = *reinterpret_cast<const v8bf*>(&As[(wrow*64 + mi*16 + fr)*BK + fq*8]);
        #pragma unroll
        for (int ni = 0; ni < 4; ++ni)
            bf[ni] = *reinterpret_cast<const v8bf*>(&Bs[(wcol*64 + ni*16 + fr)*BK + fq*8]);

        #pragma unroll
        for (int mi = 0; mi < 4; ++mi)
            #pragma unroll
            for (int ni = 0; ni < 4; ++ni)
                acc[mi][ni] = __builtin_amdgcn_mfma_f32_16x16x32_bf16(
                                  af[mi], bf[ni], acc[mi][ni], 0, 0, 0);
    }

    const int orow = m0 + wrow*64 + (lane >> 4)*4;
    const int ocol = n0 + wcol*64 + (lane & 15);
    #pragma unroll
    for (int ni = 0; ni < 4; ++ni) {
        const int col = ocol + ni*16;
        const float d = Dvec[col];
        #pragma unroll
        for (int mi = 0; mi < 4; ++mi) {
            #pragma unroll
            for (int r = 0; r < 4; ++r) {
                const size_t idx = (size_t)(orow + mi*16 + r) * N + col;
                float v = acc[mi][ni][r];
                if (d != 0.0f) v = fmaf(d, U[idx], v);   // no-op (no load) when D==0
                C[idx] = v;
            }
        }
    }
}

// ---------------------------------------------------------------------------
// weight conversions (B_w and C_w are both 262144 elems); grid (256, 2)
// ---------------------------------------------------------------------------
__global__ __launch_bounds__(256)
void cvt_w(const float4* __restrict__ Bw, const float4* __restrict__ Cw,
           ushort_t* __restrict__ Bo, ushort_t* __restrict__ Co)
{
    const int i = blockIdx.x * 256 + threadIdx.x;
    const float4* src = blockIdx.y ? Cw : Bw;
    ushort_t*     dst = blockIdx.y ? Co : Bo;
    float4 v = src[i];
    ushort4 o;
    o.x = f2bf(v.x); o.y = f2bf(v.y); o.z = f2bf(v.z); o.w = f2bf(v.w);
    *(ushort4*)&dst[4*(size_t)i] = o;
}

// ---------------------------------------------------------------------------
// exclusive carry per chunk. grid (BATCH), block=NS. Batched loads.
// ---------------------------------------------------------------------------
__global__ __launch_bounds__(256)
void carry_scan(const float* __restrict__ ll, const float* __restrict__ cf,
                float* __restrict__ carry)
{
    const int n = threadIdx.x, b = blockIdx.x;
    const float lam = sigm(ll[n]);
    float lamL = lam;                      // lam^32 (CL==32)
    #pragma unroll
    for (int i = 0; i < 5; ++i) lamL *= lamL;

    const float* cfb = cf    + (size_t)b*NCH*NS + n;
    float*       cab = carry + (size_t)b*NCH*NS + n;

    float x = 0.0f;
    for (int c0 = 0; c0 < NCH; c0 += 16) {
        float v[16];
        #pragma unroll
        for (int j = 0; j < 16; ++j) v[j] = cfb[(size_t)(c0 + j)*NS];
        #pragma unroll
        for (int j = 0; j < 16; ++j) {
            cab[(size_t)(c0 + j)*NS] = x;
            x = fmaf(lamL, x, v[j]);
        }
    }
}

// ---------------------------------------------------------------------------
// seed with carry, replay recurrence, emit bf16 hs.
// ---------------------------------------------------------------------------
__global__ __launch_bounds__(256)
void scan_apply(const float* __restrict__ Bu, const float* __restrict__ ll,
                const float* __restrict__ carry, ushort_t* __restrict__ hs16)
{
    const int n = threadIdx.x, c = blockIdx.x, b = blockIdx.y;
    const float lam = sigm(ll[n]);
    const size_t base = ((size_t)b*SEQ + (size_t)c*CL)*NS + n;

    float v[CL];
    #pragma unroll
    for (int t = 0; t < CL; ++t) v[t] = Bu[base + (size_t)t*NS];

    float h = carry[((size_t)b*NCH + c)*NS + n];
    #pragma unroll
    for (int t = 0; t < CL; ++t) { h = fmaf(lam, h, v[t]); v[t] = h; }
    #pragma unroll
    for (int t = 0; t < CL; ++t) hs16[base + (size_t)t*NS] = f2bf(v[t]);
}

// ---------------------------------------------------------------------------
extern "C" void kernel_launch(void* const* d_in, const int* in_sizes, int n_in,
                              void* d_out, int out_size, void* d_ws, size_t ws_size,
                              hipStream_t stream) {
    const float* u          = (const float*)d_in[0];
    const float* log_lambda = (const float*)d_in[1];
    const float* B_w        = (const float*)d_in[2];
    const float* C_w        = (const float*)d_in[3];
    const float* Dv         = (const float*)d_in[4];
    float* y  = (float*)d_out;

    char* w = (char*)d_ws;
    float*    Bu    = (float*)w;                       // 16.78 MB
    ushort_t* hs16  = (ushort_t*)(w + 16777216);       // 8.39 MB
    ushort_t* Bw16  = (ushort_t*)(w + 25165824);       // 512 KB
    ushort_t* Cw16  = (ushort_t*)(w + 25690112);       // 512 KB
    float*    cf    = (float*)(w + 26214400);          // 512 KB
    float*    carry = (float*)(w + 26738688);          // 512 KB

    dim3 blk(256);

    // 0) weight conversions
    cvt_w<<<dim3(256, 2), blk, 0, stream>>>((const float4*)B_w, (const float4*)C_w,
                                            Bw16, Cw16);

    // 1) Bu = u . B_w^T, fused fp32->bf16 staging + chunk finals
    gemm1_fused<<<dim3(MROWS/BM, NS/BN), blk, 0, stream>>>(
        u, Bw16, Bu, log_lambda, cf);

    // 2) carries -> apply (emit bf16 hs)
    carry_scan<<<dim3(BATCH),      blk, 0, stream>>>(log_lambda, cf, carry);
    scan_apply<<<dim3(NCH, BATCH), blk, 0, stream>>>(Bu, log_lambda, carry, hs16);

    // 3) y = hs . C_w^T + D*u
    gemm2_mfma<<<dim3(MROWS/BM, DM/BN), blk, 0, stream>>>(
        hs16, Cw16, y, MROWS, DM, NS, Dv, u);
}

// Round 5
// 182.290 us; speedup vs baseline: 2.0421x; 1.0156x over previous
//
#include <hip/hip_runtime.h>
#include <math.h>

typedef unsigned short ushort_t;
typedef __bf16 v8bf __attribute__((ext_vector_type(8)));
typedef __bf16 v4bf __attribute__((ext_vector_type(4)));
typedef float  v4f  __attribute__((ext_vector_type(4)));
typedef float  f32x4 __attribute__((ext_vector_type(4)));

#define BATCH 4
#define SEQ 4096
#define DM 1024
#define NS 256
#define MROWS (BATCH*SEQ)   // 16384

#define NCH 128
#define CL (SEQ/NCH)        // 32

#define BK 32

typedef __attribute__((address_space(1))) void as1_void;
typedef __attribute__((address_space(3))) void as3_void;

__device__ __forceinline__ void gl_lds16(const void* g, void* l) {
    __builtin_amdgcn_global_load_lds((as1_void*)g, (as3_void*)l, 16, 0, 0);
}

__device__ __forceinline__ ushort_t f2bf(float f) {
    unsigned u = __builtin_bit_cast(unsigned, f);
    u += 0x7fff + ((u >> 16) & 1);          // RNE
    return (ushort_t)(u >> 16);
}

__device__ __forceinline__ float sigm(float x) { return 1.0f / (1.0f + expf(-x)); }

__device__ __forceinline__ float powk(int e, float l1, float l2, float l4,
                                      float l8, float l16) {
    float w = 1.0f;
    if (e & 1)  w *= l1;
    if (e & 2)  w *= l2;
    if (e & 4)  w *= l4;
    if (e & 8)  w *= l8;
    if (e & 16) w *= l16;
    return w;
}

// ---------------------------------------------------------------------------
// GEMM1: Bu = u . B_w^T  + fused chunk finals cf.
// M=16384, N=256(K-state), K=1024. Tile 128x64, BK=32, 256 thr (2x2 waves,
// each 64x32 = 4x2 frags). Double-buffered LDS, one barrier per K-iter.
// A (u) staged fp32->bf16 via registers; B via global_load_lds.
// grid (NS/64, MROWS/128), x = n (fastest) for u L2 reuse.
// ---------------------------------------------------------------------------
__global__ __launch_bounds__(256)
void gemm1_fused(const float* __restrict__ A,      // u [M,K] fp32
                 const ushort_t* __restrict__ B,   // Bw16 [N,K] bf16
                 float* __restrict__ Bu,           // [M,NS] fp32
                 const float* __restrict__ ll,     // [NS]
                 float* __restrict__ cf)           // [BATCH,NCH,NS]
{
    const int K = DM;
    __shared__ __align__(16) ushort_t As[2][128*BK];  // 2 x 8 KB
    __shared__ __align__(16) ushort_t Bs[2][64*BK];   // 2 x 4 KB

    const int tid  = threadIdx.x;
    const int lane = tid & 63;
    const int wave = tid >> 6;
    const int wrow = wave >> 1;      // m offset 64*wrow
    const int wcol = wave & 1;       // n offset 32*wcol
    const int n0 = blockIdx.x * 64;
    const int m0 = blockIdx.y * 128;

    const int fr = lane & 15;
    const int fq = lane >> 4;

    // A staging coords (4 float4 chunks per thread)
    int arow[4], ac4[4];
    #pragma unroll
    for (int j = 0; j < 4; ++j) {
        int cid = j*256 + tid;
        arow[j] = cid >> 3;
        ac4[j]  = (cid & 7) * 4;
    }
    // B staging coords (1 x 16B chunk per thread; dst = wave-uniform + lane*16)
    const int brow = tid >> 2;
    const int bcol = (tid & 3) * 8;

    f32x4 acc[4][2] = {};
    v4f areg[4];

    // ---- prologue: k=0 in flight ----
    #pragma unroll
    for (int j = 0; j < 4; ++j)
        areg[j] = *(const v4f*)&A[(size_t)(m0 + arow[j])*K + ac4[j]];
    gl_lds16(&B[(size_t)(n0 + brow)*K + bcol], &Bs[0][tid*8]);

    for (int it = 0; it < K/BK; ++it) {
        const int cur = it & 1;
        // stage A regs -> LDS (bf16)
        #pragma unroll
        for (int j = 0; j < 4; ++j)
            *(v4bf*)&As[cur][arow[j]*BK + ac4[j]] = __builtin_convertvector(areg[j], v4bf);
        __syncthreads();   // drains A ds_writes + B(it) gl_lds (in flight since it-1)

        if (it + 1 < K/BK) {   // prefetch next tile; overlaps with MFMAs below
            const int k1 = (it + 1) * BK;
            gl_lds16(&B[(size_t)(n0 + brow)*K + k1 + bcol], &Bs[cur ^ 1][tid*8]);
            #pragma unroll
            for (int j = 0; j < 4; ++j)
                areg[j] = *(const v4f*)&A[(size_t)(m0 + arow[j])*K + k1 + ac4[j]];
        }

        v8bf af[4], bf[2];
        #pragma unroll
        for (int mi = 0; mi < 4; ++mi)
            af[mi] = *reinterpret_cast<const v8bf*>(&As[cur][(wrow*64 + mi*16 + fr)*BK + fq*8]);
        #pragma unroll
        for (int ni = 0; ni < 2; ++ni)
            bf[ni] = *reinterpret_cast<const v8bf*>(&Bs[cur][(wcol*32 + ni*16 + fr)*BK + fq*8]);

        #pragma unroll
        for (int mi = 0; mi < 4; ++mi)
            #pragma unroll
            for (int ni = 0; ni < 2; ++ni)
                acc[mi][ni] = __builtin_amdgcn_mfma_f32_16x16x32_bf16(
                                  af[mi], bf[ni], acc[mi][ni], 0, 0, 0);
    }

    // ---- write Bu. C/D layout: col = lane&15, row = (lane>>4)*4 + reg ----
    const int orow = m0 + wrow*64 + (lane >> 4)*4;
    const int ocol = n0 + wcol*32 + (lane & 15);
    #pragma unroll
    for (int mi = 0; mi < 4; ++mi)
        #pragma unroll
        for (int ni = 0; ni < 2; ++ni)
            #pragma unroll
            for (int r = 0; r < 4; ++r)
                Bu[(size_t)(orow + mi*16 + r) * NS + (ocol + ni*16)] = acc[mi][ni][r];

    // ---- fused chunk finals: cf[b,c,n] = sum_t lam^(31-t) Bu[c*32+t, n] ----
    const int b_idx  = m0 >> 12;
    const int c_base = (m0 & 4095) >> 5;
    const int base   = (lane >> 4) * 4;

    #pragma unroll
    for (int ni = 0; ni < 2; ++ni) {
        const int col = ocol + ni*16;
        const float l1  = sigm(ll[col]);
        const float l2  = l1*l1;
        const float l4  = l2*l2;
        const float l8  = l4*l4;
        const float l16 = l8*l8;
        #pragma unroll
        for (int half = 0; half < 2; ++half) {   // chunk within wave's 64 rows
            float f = 0.0f;
            #pragma unroll
            for (int mi2 = 0; mi2 < 2; ++mi2) {
                const int mi = half*2 + mi2;
                float w = powk(28 - mi2*16 - base, l1, l2, l4, l8, l16);
                f = fmaf(w, acc[mi][ni][3], f);
                w *= l1; f = fmaf(w, acc[mi][ni][2], f);
                w *= l1; f = fmaf(w, acc[mi][ni][1], f);
                w *= l1; f = fmaf(w, acc[mi][ni][0], f);
            }
            f += __shfl_xor(f, 16, 64);
            f += __shfl_xor(f, 32, 64);
            if ((lane >> 4) == 0) {
                const int chunk = c_base + wrow*2 + half;
                cf[((size_t)b_idx*NCH + chunk)*NS + col] = f;
            }
        }
    }
}

// ---------------------------------------------------------------------------
// GEMM2: y = hs . C_w^T (+ D*u per-element when D!=0).
// M=16384, N=1024, K=256. Tile 128x128, BK=32, 256 thr (2x2 waves of 64x64).
// Double-buffered LDS, both operands via global_load_lds.
// grid (N/128, M/128) = (8, 128) = 1024 blocks = 4/CU.
// ---------------------------------------------------------------------------
__global__ __launch_bounds__(256)
void gemm2_mfma(const ushort_t* __restrict__ A,  // hs16 [M,256] bf16
                const ushort_t* __restrict__ B,  // Cw16 [1024,256] bf16
                float* __restrict__ C,           // y [M,1024] fp32
                const float* __restrict__ Dvec, const float* __restrict__ U)
{
    const int K = NS;
    const int N = DM;
    __shared__ __align__(16) ushort_t As[2][128*BK];  // 2 x 8 KB
    __shared__ __align__(16) ushort_t Bs[2][128*BK];  // 2 x 8 KB

    const int tid  = threadIdx.x;
    const int lane = tid & 63;
    const int wave = tid >> 6;
    const int wrow = wave >> 1;
    const int wcol = wave & 1;
    const int n0 = blockIdx.x * 128;
    const int m0 = blockIdx.y * 128;

    const int fr = lane & 15;
    const int fq = lane >> 4;

    f32x4 acc[4][4] = {};

    const int ch0 = wave*128 + lane;    // 512 x 16B chunks, 2/thread
    const int ch1 = ch0 + 64;
    const int r0 = ch0 >> 2, c0 = (ch0 & 3) * 8;
    const int r1 = ch1 >> 2, c1 = (ch1 & 3) * 8;

    // prologue
    gl_lds16(&A[(size_t)(m0 + r0)*K + c0], &As[0][ch0*8]);
    gl_lds16(&B[(size_t)(n0 + r0)*K + c0], &Bs[0][ch0*8]);
    gl_lds16(&A[(size_t)(m0 + r1)*K + c1], &As[0][ch1*8]);
    gl_lds16(&B[(size_t)(n0 + r1)*K + c1], &Bs[0][ch1*8]);

    for (int it = 0; it < K/BK; ++it) {
        const int cur = it & 1;
        __syncthreads();   // drains tile(it) gl_lds, in flight since it-1

        if (it + 1 < K/BK) {
            const int k1 = (it + 1) * BK;
            gl_lds16(&A[(size_t)(m0 + r0)*K + k1 + c0], &As[cur^1][ch0*8]);
            gl_lds16(&B[(size_t)(n0 + r0)*K + k1 + c0], &Bs[cur^1][ch0*8]);
            gl_lds16(&A[(size_t)(m0 + r1)*K + k1 + c1], &As[cur^1][ch1*8]);
            gl_lds16(&B[(size_t)(n0 + r1)*K + k1 + c1], &Bs[cur^1][ch1*8]);
        }

        v8bf af[4], bf[4];
        #pragma unroll
        for (int mi = 0; mi < 4; ++mi)
            af[mi] = *reinterpret_cast<const v8bf*>(&As[cur][(wrow*64 + mi*16 + fr)*BK + fq*8]);
        #pragma unroll
        for (int ni = 0; ni < 4; ++ni)
            bf[ni] = *reinterpret_cast<const v8bf*>(&Bs[cur][(wcol*64 + ni*16 + fr)*BK + fq*8]);

        #pragma unroll
        for (int mi = 0; mi < 4; ++mi)
            #pragma unroll
            for (int ni = 0; ni < 4; ++ni)
                acc[mi][ni] = __builtin_amdgcn_mfma_f32_16x16x32_bf16(
                                  af[mi], bf[ni], acc[mi][ni], 0, 0, 0);
    }

    const int orow = m0 + wrow*64 + (lane >> 4)*4;
    const int ocol = n0 + wcol*64 + (lane & 15);
    #pragma unroll
    for (int ni = 0; ni < 4; ++ni) {
        const int col = ocol + ni*16;
        const float d = Dvec[col];
        #pragma unroll
        for (int mi = 0; mi < 4; ++mi) {
            #pragma unroll
            for (int r = 0; r < 4; ++r) {
                const size_t idx = (size_t)(orow + mi*16 + r) * N + col;
                float v = acc[mi][ni][r];
                if (d != 0.0f) v = fmaf(d, U[idx], v);   // no load when D==0
                C[idx] = v;
            }
        }
    }
}

// ---------------------------------------------------------------------------
__global__ __launch_bounds__(256)
void cvt_w(const float4* __restrict__ Bw, const float4* __restrict__ Cw,
           ushort_t* __restrict__ Bo, ushort_t* __restrict__ Co)
{
    const int i = blockIdx.x * 256 + threadIdx.x;
    const float4* src = blockIdx.y ? Cw : Bw;
    ushort_t*     dst = blockIdx.y ? Co : Bo;
    float4 v = src[i];
    ushort4 o;
    o.x = f2bf(v.x); o.y = f2bf(v.y); o.z = f2bf(v.z); o.w = f2bf(v.w);
    *(ushort4*)&dst[4*(size_t)i] = o;
}

// ---------------------------------------------------------------------------
__global__ __launch_bounds__(256)
void carry_scan(const float* __restrict__ ll, const float* __restrict__ cf,
                float* __restrict__ carry)
{
    const int n = threadIdx.x, b = blockIdx.x;
    const float lam = sigm(ll[n]);
    float lamL = lam;
    #pragma unroll
    for (int i = 0; i < 5; ++i) lamL *= lamL;   // lam^32

    const float* cfb = cf    + (size_t)b*NCH*NS + n;
    float*       cab = carry + (size_t)b*NCH*NS + n;

    float x = 0.0f;
    for (int c0 = 0; c0 < NCH; c0 += 16) {
        float v[16];
        #pragma unroll
        for (int j = 0; j < 16; ++j) v[j] = cfb[(size_t)(c0 + j)*NS];
        #pragma unroll
        for (int j = 0; j < 16; ++j) {
            cab[(size_t)(c0 + j)*NS] = x;
            x = fmaf(lamL, x, v[j]);
        }
    }
}

// ---------------------------------------------------------------------------
__global__ __launch_bounds__(256)
void scan_apply(const float* __restrict__ Bu, const float* __restrict__ ll,
                const float* __restrict__ carry, ushort_t* __restrict__ hs16)
{
    const int n = threadIdx.x, c = blockIdx.x, b = blockIdx.y;
    const float lam = sigm(ll[n]);
    const size_t base = ((size_t)b*SEQ + (size_t)c*CL)*NS + n;

    float v[CL];
    #pragma unroll
    for (int t = 0; t < CL; ++t) v[t] = Bu[base + (size_t)t*NS];

    float h = carry[((size_t)b*NCH + c)*NS + n];
    #pragma unroll
    for (int t = 0; t < CL; ++t) { h = fmaf(lam, h, v[t]); v[t] = h; }
    #pragma unroll
    for (int t = 0; t < CL; ++t) hs16[base + (size_t)t*NS] = f2bf(v[t]);
}

// ---------------------------------------------------------------------------
extern "C" void kernel_launch(void* const* d_in, const int* in_sizes, int n_in,
                              void* d_out, int out_size, void* d_ws, size_t ws_size,
                              hipStream_t stream) {
    const float* u          = (const float*)d_in[0];
    const float* log_lambda = (const float*)d_in[1];
    const float* B_w        = (const float*)d_in[2];
    const float* C_w        = (const float*)d_in[3];
    const float* Dv         = (const float*)d_in[4];
    float* y  = (float*)d_out;

    char* w = (char*)d_ws;
    float*    Bu    = (float*)w;                       // 16.78 MB
    ushort_t* hs16  = (ushort_t*)(w + 16777216);       // 8.39 MB
    ushort_t* Bw16  = (ushort_t*)(w + 25165824);       // 512 KB
    ushort_t* Cw16  = (ushort_t*)(w + 25690112);       // 512 KB
    float*    cf    = (float*)(w + 26214400);          // 512 KB
    float*    carry = (float*)(w + 26738688);          // 512 KB

    dim3 blk(256);

    // 0) weight conversions
    cvt_w<<<dim3(256, 2), blk, 0, stream>>>((const float4*)B_w, (const float4*)C_w,
                                            Bw16, Cw16);

    // 1) Bu = u . B_w^T, fused fp32->bf16 staging + chunk finals
    gemm1_fused<<<dim3(NS/64, MROWS/128), blk, 0, stream>>>(
        u, Bw16, Bu, log_lambda, cf);

    // 2) carries -> apply (emit bf16 hs)
    carry_scan<<<dim3(BATCH),      blk, 0, stream>>>(log_lambda, cf, carry);
    scan_apply<<<dim3(NCH, BATCH), blk, 0, stream>>>(Bu, log_lambda, carry, hs16);

    // 3) y = hs . C_w^T + D*u
    gemm2_mfma<<<dim3(DM/128, MROWS/128), blk, 0, stream>>>(
        hs16, Cw16, y, Dv, u);
}

// Round 6
// 173.394 us; speedup vs baseline: 2.1469x; 1.0513x over previous
//
#include <hip/hip_runtime.h>
#include <math.h>

typedef unsigned short ushort_t;
typedef __bf16 v8bf __attribute__((ext_vector_type(8)));
typedef __bf16 v4bf __attribute__((ext_vector_type(4)));
typedef float  v4f  __attribute__((ext_vector_type(4)));
typedef float  f32x4 __attribute__((ext_vector_type(4)));

#define BATCH 4
#define SEQ 4096
#define DM 1024
#define NS 256
#define MROWS (BATCH*SEQ)   // 16384

#define NCH 128
#define CL (SEQ/NCH)        // 32

#define BK 32
#define KSPLIT 2
#define KHALF (DM/KSPLIT)   // 512

typedef __attribute__((address_space(1))) void as1_void;
typedef __attribute__((address_space(3))) void as3_void;

__device__ __forceinline__ void gl_lds16(const void* g, void* l) {
    __builtin_amdgcn_global_load_lds((as1_void*)g, (as3_void*)l, 16, 0, 0);
}

__device__ __forceinline__ ushort_t f2bf(float f) {
    unsigned u = __builtin_bit_cast(unsigned, f);
    u += 0x7fff + ((u >> 16) & 1);          // RNE
    return (ushort_t)(u >> 16);
}

__device__ __forceinline__ float sigm(float x) { return 1.0f / (1.0f + expf(-x)); }

__device__ __forceinline__ float powk(int e, float l1, float l2, float l4,
                                      float l8, float l16) {
    float w = 1.0f;
    if (e & 1)  w *= l1;
    if (e & 2)  w *= l2;
    if (e & 4)  w *= l4;
    if (e & 8)  w *= l8;
    if (e & 16) w *= l16;
    return w;
}

// ---------------------------------------------------------------------------
// GEMM1: Bu_k = u[:, k-half] . B_w[:, k-half]^T  (partial), + partial chunk
// finals cf_k. Tile 64(m) x 256(n = full state dim) so each u element is
// fetched by exactly ONE block. K split in 2 -> grid (KSPLIT, 256) = 512
// blocks = 2/CU. Double-buffered LDS, one barrier/iter. A staged
// fp32->bf16 via regs; B via global_load_lds. Downstream sums the partials
// (linear), so no reduction needed here.
// ---------------------------------------------------------------------------
__global__ __launch_bounds__(256)
void gemm1_fused(const float* __restrict__ A,      // u [M,K] fp32
                 const ushort_t* __restrict__ B,   // Bw16 [NS,K] bf16
                 float* __restrict__ BuP,          // [KSPLIT,M,NS] fp32 partials
                 const float* __restrict__ ll,     // [NS]
                 float* __restrict__ cfP)          // [KSPLIT,BATCH,NCH,NS]
{
    const int K = DM;
    __shared__ __align__(16) ushort_t As[2][64*BK];   // 2 x 4 KB
    __shared__ __align__(16) ushort_t Bs[2][256*BK];  // 2 x 16 KB

    const int tid  = threadIdx.x;
    const int lane = tid & 63;
    const int wave = tid >> 6;       // n-quadrant: cols wave*64..wave*64+63
    const int kidx = blockIdx.x;     // k-half
    const int m0   = blockIdx.y * 64;
    const int kb   = kidx * KHALF;

    const int fr = lane & 15;
    const int fq = lane >> 4;

    // A staging: 64x32 fp32 = 512 float4 chunks, 2/thread
    int arow[2], ac4[2];
    #pragma unroll
    for (int j = 0; j < 2; ++j) {
        int cid = j*256 + tid;
        arow[j] = cid >> 3;
        ac4[j]  = (cid & 7) * 4;
    }
    // B staging: 256x32 bf16 = 1024 x 16B chunks, 4/thread (lane-contig dst)
    int brow[4], bc[4];
    #pragma unroll
    for (int j = 0; j < 4; ++j) {
        int cid = j*256 + tid;
        brow[j] = cid >> 2;
        bc[j]   = (cid & 3) * 8;
    }

    f32x4 acc[4][4] = {};   // [mi][ni] : m = mi*16.., n = wave*64 + ni*16..
    v4f areg[2];

    // ---- prologue ----
    #pragma unroll
    for (int j = 0; j < 2; ++j)
        areg[j] = *(const v4f*)&A[(size_t)(m0 + arow[j])*K + kb + ac4[j]];
    #pragma unroll
    for (int j = 0; j < 4; ++j)
        gl_lds16(&B[(size_t)brow[j]*K + kb + bc[j]], &Bs[0][(j*256 + tid)*8]);

    for (int it = 0; it < KHALF/BK; ++it) {
        const int cur = it & 1;
        #pragma unroll
        for (int j = 0; j < 2; ++j)
            *(v4bf*)&As[cur][arow[j]*BK + ac4[j]] = __builtin_convertvector(areg[j], v4bf);
        __syncthreads();

        if (it + 1 < KHALF/BK) {
            const int k1 = kb + (it + 1) * BK;
            #pragma unroll
            for (int j = 0; j < 4; ++j)
                gl_lds16(&B[(size_t)brow[j]*K + k1 + bc[j]], &Bs[cur^1][(j*256 + tid)*8]);
            #pragma unroll
            for (int j = 0; j < 2; ++j)
                areg[j] = *(const v4f*)&A[(size_t)(m0 + arow[j])*K + k1 + ac4[j]];
        }

        v8bf af[4], bf[4];
        #pragma unroll
        for (int mi = 0; mi < 4; ++mi)
            af[mi] = *reinterpret_cast<const v8bf*>(&As[cur][(mi*16 + fr)*BK + fq*8]);
        #pragma unroll
        for (int ni = 0; ni < 4; ++ni)
            bf[ni] = *reinterpret_cast<const v8bf*>(&Bs[cur][(wave*64 + ni*16 + fr)*BK + fq*8]);

        #pragma unroll
        for (int mi = 0; mi < 4; ++mi)
            #pragma unroll
            for (int ni = 0; ni < 4; ++ni)
                acc[mi][ni] = __builtin_amdgcn_mfma_f32_16x16x32_bf16(
                                  af[mi], bf[ni], acc[mi][ni], 0, 0, 0);
    }

    // ---- write partial Bu. C/D layout: col=lane&15, row=(lane>>4)*4+reg ----
    float* Bu = BuP + (size_t)kidx*MROWS*NS;
    const int base = (lane >> 4) * 4;
    #pragma unroll
    for (int mi = 0; mi < 4; ++mi) {
        #pragma unroll
        for (int ni = 0; ni < 4; ++ni) {
            const int col = wave*64 + ni*16 + fr;
            #pragma unroll
            for (int r = 0; r < 4; ++r)
                Bu[(size_t)(m0 + mi*16 + base + r)*NS + col] = acc[mi][ni][r];
        }
    }

    // ---- partial chunk finals: cf_k[b,c,n] = sum_t lam^(31-t) BuP[c*32+t,n]
    // block rows = 2 chunks (h=0,1); chunk h uses mi = 2h+mi2, rowin =
    // mi2*16 + base + r, weight lam^(31-rowin).
    const int b_idx  = m0 >> 12;
    const int c_base = (m0 & 4095) >> 5;
    float* cfk = cfP + (size_t)kidx*BATCH*NCH*NS;

    #pragma unroll
    for (int ni = 0; ni < 4; ++ni) {
        const int col = wave*64 + ni*16 + fr;
        const float l1  = sigm(ll[col]);
        const float l2  = l1*l1;
        const float l4  = l2*l2;
        const float l8  = l4*l4;
        const float l16 = l8*l8;
        #pragma unroll
        for (int h = 0; h < 2; ++h) {
            float f = 0.0f;
            #pragma unroll
            for (int mi2 = 0; mi2 < 2; ++mi2) {
                const int mi = 2*h + mi2;
                float w = powk(28 - mi2*16 - base, l1, l2, l4, l8, l16);
                f = fmaf(w, acc[mi][ni][3], f);
                w *= l1; f = fmaf(w, acc[mi][ni][2], f);
                w *= l1; f = fmaf(w, acc[mi][ni][1], f);
                w *= l1; f = fmaf(w, acc[mi][ni][0], f);
            }
            f += __shfl_xor(f, 16, 64);
            f += __shfl_xor(f, 32, 64);
            if ((lane >> 4) == 0) {
                const int chunk = c_base + h;
                cfk[((size_t)b_idx*NCH + chunk)*NS + col] = f;
            }
        }
    }
}

// ---------------------------------------------------------------------------
// GEMM2: y = hs . C_w^T (+ D*u per-element when D!=0).
// 128x128 tile, BK=32, dbuf, grid (8,128) = 1024 blocks = 4/CU.
// ---------------------------------------------------------------------------
__global__ __launch_bounds__(256)
void gemm2_mfma(const ushort_t* __restrict__ A,  // hs16 [M,256] bf16
                const ushort_t* __restrict__ B,  // Cw16 [1024,256] bf16
                float* __restrict__ C,           // y [M,1024] fp32
                const float* __restrict__ Dvec, const float* __restrict__ U)
{
    const int K = NS;
    const int N = DM;
    __shared__ __align__(16) ushort_t As[2][128*BK];
    __shared__ __align__(16) ushort_t Bs[2][128*BK];

    const int tid  = threadIdx.x;
    const int lane = tid & 63;
    const int wave = tid >> 6;
    const int wrow = wave >> 1;
    const int wcol = wave & 1;
    const int n0 = blockIdx.x * 128;
    const int m0 = blockIdx.y * 128;

    const int fr = lane & 15;
    const int fq = lane >> 4;

    f32x4 acc[4][4] = {};

    const int ch0 = wave*128 + lane;
    const int ch1 = ch0 + 64;
    const int r0 = ch0 >> 2, c0 = (ch0 & 3) * 8;
    const int r1 = ch1 >> 2, c1 = (ch1 & 3) * 8;

    gl_lds16(&A[(size_t)(m0 + r0)*K + c0], &As[0][ch0*8]);
    gl_lds16(&B[(size_t)(n0 + r0)*K + c0], &Bs[0][ch0*8]);
    gl_lds16(&A[(size_t)(m0 + r1)*K + c1], &As[0][ch1*8]);
    gl_lds16(&B[(size_t)(n0 + r1)*K + c1], &Bs[0][ch1*8]);

    for (int it = 0; it < K/BK; ++it) {
        const int cur = it & 1;
        __syncthreads();

        if (it + 1 < K/BK) {
            const int k1 = (it + 1) * BK;
            gl_lds16(&A[(size_t)(m0 + r0)*K + k1 + c0], &As[cur^1][ch0*8]);
            gl_lds16(&B[(size_t)(n0 + r0)*K + k1 + c0], &Bs[cur^1][ch0*8]);
            gl_lds16(&A[(size_t)(m0 + r1)*K + k1 + c1], &As[cur^1][ch1*8]);
            gl_lds16(&B[(size_t)(n0 + r1)*K + k1 + c1], &Bs[cur^1][ch1*8]);
        }

        v8bf af[4], bf[4];
        #pragma unroll
        for (int mi = 0; mi < 4; ++mi)
            af[mi] = *reinterpret_cast<const v8bf*>(&As[cur][(wrow*64 + mi*16 + fr)*BK + fq*8]);
        #pragma unroll
        for (int ni = 0; ni < 4; ++ni)
            bf[ni] = *reinterpret_cast<const v8bf*>(&Bs[cur][(wcol*64 + ni*16 + fr)*BK + fq*8]);

        #pragma unroll
        for (int mi = 0; mi < 4; ++mi)
            #pragma unroll
            for (int ni = 0; ni < 4; ++ni)
                acc[mi][ni] = __builtin_amdgcn_mfma_f32_16x16x32_bf16(
                                  af[mi], bf[ni], acc[mi][ni], 0, 0, 0);
    }

    const int orow = m0 + wrow*64 + (lane >> 4)*4;
    const int ocol = n0 + wcol*64 + (lane & 15);
    #pragma unroll
    for (int ni = 0; ni < 4; ++ni) {
        const int col = ocol + ni*16;
        const float d = Dvec[col];
        #pragma unroll
        for (int mi = 0; mi < 4; ++mi) {
            #pragma unroll
            for (int r = 0; r < 4; ++r) {
                const size_t idx = (size_t)(orow + mi*16 + r) * N + col;
                float v = acc[mi][ni][r];
                if (d != 0.0f) v = fmaf(d, U[idx], v);   // no load when D==0
                C[idx] = v;
            }
        }
    }
}

// ---------------------------------------------------------------------------
__global__ __launch_bounds__(256)
void cvt_w(const float4* __restrict__ Bw, const float4* __restrict__ Cw,
           ushort_t* __restrict__ Bo, ushort_t* __restrict__ Co)
{
    const int i = blockIdx.x * 256 + threadIdx.x;
    const float4* src = blockIdx.y ? Cw : Bw;
    ushort_t*     dst = blockIdx.y ? Co : Bo;
    float4 v = src[i];
    ushort4 o;
    o.x = f2bf(v.x); o.y = f2bf(v.y); o.z = f2bf(v.z); o.w = f2bf(v.w);
    *(ushort4*)&dst[4*(size_t)i] = o;
}

// ---------------------------------------------------------------------------
// exclusive carry per chunk; sums the two cf partials. grid (BATCH), blk=NS.
// ---------------------------------------------------------------------------
__global__ __launch_bounds__(256)
void carry_scan(const float* __restrict__ ll, const float* __restrict__ cfP,
                float* __restrict__ carry)
{
    const int n = threadIdx.x, b = blockIdx.x;
    const float lam = sigm(ll[n]);
    float lamL = lam;
    #pragma unroll
    for (int i = 0; i < 5; ++i) lamL *= lamL;   // lam^32

    const float* cf0 = cfP + (size_t)b*NCH*NS + n;
    const float* cf1 = cf0 + (size_t)BATCH*NCH*NS;
    float*       cab = carry + (size_t)b*NCH*NS + n;

    float x = 0.0f;
    for (int c0 = 0; c0 < NCH; c0 += 16) {
        float v[16];
        #pragma unroll
        for (int j = 0; j < 16; ++j)
            v[j] = cf0[(size_t)(c0 + j)*NS] + cf1[(size_t)(c0 + j)*NS];
        #pragma unroll
        for (int j = 0; j < 16; ++j) {
            cab[(size_t)(c0 + j)*NS] = x;
            x = fmaf(lamL, x, v[j]);
        }
    }
}

// ---------------------------------------------------------------------------
// seed with carry, sum Bu partials, replay recurrence, emit bf16 hs.
// ---------------------------------------------------------------------------
__global__ __launch_bounds__(256)
void scan_apply(const float* __restrict__ BuP, const float* __restrict__ ll,
                const float* __restrict__ carry, ushort_t* __restrict__ hs16)
{
    const int n = threadIdx.x, c = blockIdx.x, b = blockIdx.y;
    const float lam = sigm(ll[n]);
    const size_t base = ((size_t)b*SEQ + (size_t)c*CL)*NS + n;
    const float* Bu0 = BuP;
    const float* Bu1 = BuP + (size_t)MROWS*NS;

    float v[CL];
    #pragma unroll
    for (int t = 0; t < CL; ++t)
        v[t] = Bu0[base + (size_t)t*NS] + Bu1[base + (size_t)t*NS];

    float h = carry[((size_t)b*NCH + c)*NS + n];
    #pragma unroll
    for (int t = 0; t < CL; ++t) { h = fmaf(lam, h, v[t]); v[t] = h; }
    #pragma unroll
    for (int t = 0; t < CL; ++t) hs16[base + (size_t)t*NS] = f2bf(v[t]);
}

// ---------------------------------------------------------------------------
extern "C" void kernel_launch(void* const* d_in, const int* in_sizes, int n_in,
                              void* d_out, int out_size, void* d_ws, size_t ws_size,
                              hipStream_t stream) {
    const float* u          = (const float*)d_in[0];
    const float* log_lambda = (const float*)d_in[1];
    const float* B_w        = (const float*)d_in[2];
    const float* C_w        = (const float*)d_in[3];
    const float* Dv         = (const float*)d_in[4];
    float* y  = (float*)d_out;

    char* w = (char*)d_ws;
    float*    BuP   = (float*)w;                       // 2 x 16.78 MB partials
    ushort_t* hs16  = (ushort_t*)(w + 33554432);       // 8.39 MB
    ushort_t* Bw16  = (ushort_t*)(w + 41943040);       // 512 KB
    ushort_t* Cw16  = (ushort_t*)(w + 42467328);       // 512 KB
    float*    cfP   = (float*)(w + 42991616);          // 2 x 512 KB partials
    float*    carry = (float*)(w + 44040192);          // 512 KB

    dim3 blk(256);

    // 0) weight conversions
    cvt_w<<<dim3(256, 2), blk, 0, stream>>>((const float4*)B_w, (const float4*)C_w,
                                            Bw16, Cw16);

    // 1) Bu partials = u . B_w^T (K-split), fused cvt + partial chunk finals
    gemm1_fused<<<dim3(KSPLIT, MROWS/64), blk, 0, stream>>>(
        u, Bw16, BuP, log_lambda, cfP);

    // 2) carries (sum partials) -> apply (sum partials, emit bf16 hs)
    carry_scan<<<dim3(BATCH),      blk, 0, stream>>>(log_lambda, cfP, carry);
    scan_apply<<<dim3(NCH, BATCH), blk, 0, stream>>>(BuP, log_lambda, carry, hs16);

    // 3) y = hs . C_w^T + D*u
    gemm2_mfma<<<dim3(DM/128, MROWS/128), blk, 0, stream>>>(
        hs16, Cw16, y, Dv, u);
}